// Round 7
// baseline (390.761 us; speedup 1.0000x reference)
//
#include <hip/hip_runtime.h>

// B=4, DIN=DM=256, N=256, L=64, H=4, LH=16.
// Block = (b, n, head-pair): grid = 2048, 512 threads (8 waves).
// Round-7: q kept in registers (QT region eliminated -> LDS 50 KB -> 3 blocks/CU),
// sequential-head online softmax (r2's low-VGPR envelope), shfl-halved exchanges,
// exp2 softmax (QSCALE folded into q epilogue), tree max/sum, first-tile peel.
// All LDS layouts / MFMA index math carried from the r2/r6 PASSING kernels.

typedef unsigned int u32;
typedef unsigned short u16;
typedef __attribute__((ext_vector_type(8))) short s8v;    // 8 x bf16
typedef __attribute__((ext_vector_type(16))) float f16v;  // 16 x f32 acc

// LDS (u16 indices): XS [cblk32][l32][j8] (X^T blocked; ATT after attention)
//                    KT [lblk4][e256][j8]  (k^T blocked)
//                    VT [eblk32][l32][j8]  (v blocked)
// Staging overlays: LINQ @8192 (dead KT+VT head), LINKV @16384 (dead VT+pad).
#define XS 0
#define KT 8192
#define VT 16384
#define LINQ 8192
#define LINKV 16384
#define LDS_TOT 25600   // 50 KB -> 3 blocks/CU
#define LSTR 36         // linear staging row stride (u16)

#define QSCALE 0.360673760222f   // 0.25 * log2(e)

__device__ __forceinline__ u16 f2bf(float x) {          // RNE bit-twiddle (verified)
  union { float f; u32 u; } c; c.f = x;
  return (u16)((c.u + 0x7FFFu + ((c.u >> 16) & 1u)) >> 16);
}
__device__ __forceinline__ u32 pk2(float a, float b) {  // lo=a, hi=b
  return (u32)f2bf(a) | ((u32)f2bf(b) << 16);
}
__device__ __forceinline__ float xh_max(float v) { return fmaxf(v, __shfl_xor(v, 32)); }
__device__ __forceinline__ float xh_sum(float v) { return v + __shfl_xor(v, 32); }

__global__ void cvt_weights(const float* __restrict__ wq, const float* __restrict__ wk,
                            const float* __restrict__ wv, const float* __restrict__ wo,
                            u16* __restrict__ out) {
  int i = blockIdx.x * 256 + threadIdx.x;  // 0..65535
  out[i]          = f2bf(wq[i]);
  out[i + 65536]  = f2bf(wk[i]);
  out[i + 131072] = f2bf(wv[i]);
  out[i + 196608] = f2bf(wo[i]);
}

// global fp32 X[c][l-window 32] -> linear bf16 lds[linoff + c*LSTR + l]
__device__ __forceinline__ void stage_lin(const float* __restrict__ src, u16* lds,
                                          int linoff, int tid) {
#pragma unroll
  for (int it = 0; it < 4; ++it) {
    int f4 = it * 512 + tid;           // 0..2047 float4s
    int c = f4 >> 3;
    int l4 = (f4 & 7) << 2;
    const float4 v = *reinterpret_cast<const float4*>(src + c * 16384 + l4);
    uint2 w; w.x = pk2(v.x, v.y); w.y = pk2(v.z, v.w);
    *reinterpret_cast<uint2*>(&lds[linoff + c * LSTR + l4]) = w;
  }
}

// linear lds[c][l] -> blocked XS[cblk][l][j]
__device__ __forceinline__ void lin_to_xs(u16* lds, int linoff, int tid) {
#pragma unroll
  for (int it = 0; it < 2; ++it) {
    int idx = it * 512 + tid;          // (cblk, l)
    int l = idx & 31, cb = idx >> 5;
    int sb = linoff + cb * (8 * LSTR) + l;
    u32 u0 = (u32)lds[sb]            | ((u32)lds[sb + LSTR]     << 16);
    u32 u1 = (u32)lds[sb + 2 * LSTR] | ((u32)lds[sb + 3 * LSTR] << 16);
    u32 u2 = (u32)lds[sb + 4 * LSTR] | ((u32)lds[sb + 5 * LSTR] << 16);
    u32 u3 = (u32)lds[sb + 6 * LSTR] | ((u32)lds[sb + 7 * LSTR] << 16);
    union { u32 u[4]; s8v v; } pw;
    pw.u[0] = u0; pw.u[1] = u1; pw.u[2] = u2; pw.u[3] = u3;
    *reinterpret_cast<s8v*>(&lds[XS + cb * 256 + l * 8]) = pw.v;
  }
}

// q projection -> B-frags in registers (no LDS round trip).
// Wave computes o = wid*32+lo; acc reg 4g+i holds l = 8g+4hi+i.
// Frag for head h needs l = 16h + 8hi + j (j=0..7).
__device__ __forceinline__ void proj_Q(u16* lds, const u16* __restrict__ w,
                                       const float* __restrict__ bias,
                                       s8v qf[2], int wid, int lo, int hi) {
  const int o = wid * 32 + lo;
  f16v a;
#pragma unroll
  for (int i = 0; i < 16; ++i) a[i] = 0.f;
#pragma unroll
  for (int s = 0; s < 16; ++s) {
    const s8v bw = *reinterpret_cast<const s8v*>(w + o * 256 + s * 16 + hi * 8);
    const s8v xf = *reinterpret_cast<const s8v*>(&lds[XS + (2 * s + hi) * 256 + lo * 8]);
    a = __builtin_amdgcn_mfma_f32_32x32x16_bf16(xf, bw, a, 0, 0, 0);
  }
  const float bb = bias[o];
  u32 W[8];   // word 2g   = (l=8g+4hi+0, +1), word 2g+1 = (l=8g+4hi+2, +3)
#pragma unroll
  for (int g = 0; g < 4; ++g) {
    W[2 * g]     = pk2((a[4 * g + 0] + bb) * QSCALE, (a[4 * g + 1] + bb) * QSCALE);
    W[2 * g + 1] = pk2((a[4 * g + 2] + bb) * QSCALE, (a[4 * g + 3] + bb) * QSCALE);
  }
#pragma unroll
  for (int h = 0; h < 2; ++h) {
    const int bse = 4 * h;   // words A,B = W[bse],W[bse+1] (lblk 2h); C,D = W[bse+2..3] (lblk 2h+1)
    // hi=0 lane: needs own A,B (l=16h+0..3) + partner's A,B (l=16h+4..7)
    // hi=1 lane: needs partner's C,D (l=16h+8..11) + own C,D (l=16h+12..15)
    const u32 z0 = hi ? W[bse + 0] : W[bse + 2];
    const u32 z1 = hi ? W[bse + 1] : W[bse + 3];
    const u32 s0 = (u32)__shfl_xor((int)z0, 32);
    const u32 s1 = (u32)__shfl_xor((int)z1, 32);
    union { u32 u[4]; s8v v; } fu;
    fu.u[0] = hi ? s0 : W[bse + 0];
    fu.u[1] = hi ? s1 : W[bse + 1];
    fu.u[2] = hi ? W[bse + 2] : s0;
    fu.u[3] = hi ? W[bse + 3] : s1;
    qf[h] = fu.v;
  }
}

// k^T: D[l][o] = sum_c X^T[l][c] W[o][c] + b[o] -> KT [lblk][o][j]
__device__ __forceinline__ void proj_K(u16* lds, const u16* __restrict__ w,
                                       const float* __restrict__ bias,
                                       int wid, int lo, int hi) {
  const int o = wid * 32 + lo;
  f16v a;
#pragma unroll
  for (int i = 0; i < 16; ++i) a[i] = 0.f;
#pragma unroll
  for (int s = 0; s < 16; ++s) {
    const s8v bw = *reinterpret_cast<const s8v*>(w + o * 256 + s * 16 + hi * 8);
    const s8v xf = *reinterpret_cast<const s8v*>(&lds[XS + (2 * s + hi) * 256 + lo * 8]);
    a = __builtin_amdgcn_mfma_f32_32x32x16_bf16(xf, bw, a, 0, 0, 0);
  }
  const float bb = bias[o];
#pragma unroll
  for (int g = 0; g < 4; ++g) {
    uint2 wv2;
    wv2.x = pk2(a[4 * g + 0] + bb, a[4 * g + 1] + bb);
    wv2.y = pk2(a[4 * g + 2] + bb, a[4 * g + 3] + bb);
    *reinterpret_cast<uint2*>(&lds[KT + g * 2048 + o * 8 + hi * 4]) = wv2;
  }
}

// v: D[e][l] = sum_c Wv[e][c] X[c][l] + bv[e] -> VT [eblk][l][j]
__device__ __forceinline__ void proj_V(u16* lds, const u16* __restrict__ w,
                                       const float* __restrict__ bias,
                                       int wid, int lo, int hi) {
  const int e0 = wid * 32;
  const int e = e0 + lo;
  f16v a;
#pragma unroll
  for (int i = 0; i < 16; ++i) a[i] = 0.f;
#pragma unroll
  for (int s = 0; s < 16; ++s) {
    const s8v aw = *reinterpret_cast<const s8v*>(w + e * 256 + s * 16 + hi * 8);
    const s8v xf = *reinterpret_cast<const s8v*>(&lds[XS + (2 * s + hi) * 256 + lo * 8]);
    a = __builtin_amdgcn_mfma_f32_32x32x16_bf16(aw, xf, a, 0, 0, 0);
  }
#pragma unroll
  for (int g = 0; g < 4; ++g) {
    const int eb = e0 + 8 * g + 4 * hi;
    uint2 wv2;
    wv2.x = pk2(a[4 * g + 0] + bias[eb + 0], a[4 * g + 1] + bias[eb + 1]);
    wv2.y = pk2(a[4 * g + 2] + bias[eb + 2], a[4 * g + 3] + bias[eb + 3]);
    *reinterpret_cast<uint2*>(&lds[VT + (4 * wid + g) * 256 + lo * 8 + hi * 4]) = wv2;
  }
}

// out[o][l] = sum_d Wo[o][d] att[d][l] + bo[o]  (att lives in XS)
__device__ __forceinline__ void proj_O(u16* lds, const u16* __restrict__ w,
                                       const float* __restrict__ bias,
                                       float* __restrict__ out, long obase,
                                       int wid, int lo, int hi) {
  const int o0 = wid * 32;
  const int o = o0 + lo;
  f16v a;
#pragma unroll
  for (int i = 0; i < 16; ++i) a[i] = 0.f;
#pragma unroll
  for (int s = 0; s < 16; ++s) {
    const s8v aw = *reinterpret_cast<const s8v*>(w + o * 256 + s * 16 + hi * 8);
    const s8v bf = *reinterpret_cast<const s8v*>(&lds[XS + (2 * s + hi) * 256 + lo * 8]);
    a = __builtin_amdgcn_mfma_f32_32x32x16_bf16(aw, bf, a, 0, 0, 0);
  }
#pragma unroll
  for (int r = 0; r < 16; ++r) {
    const int orow = o0 + (r & 3) + 8 * (r >> 2) + 4 * hi;
    out[obase + orow * 16384 + lo] = a[r] + bias[orow];
  }
}

__global__ __launch_bounds__(512, 6)
void mha_kernel(const float* __restrict__ xq, const float* __restrict__ xk,
                const float* __restrict__ xv, const u16* __restrict__ wb,
                const float* __restrict__ bq, const float* __restrict__ bk,
                const float* __restrict__ bv, const float* __restrict__ bo,
                float* __restrict__ out) {
  __shared__ __align__(16) u16 lds[LDS_TOT];
  const int tid = threadIdx.x;
  const int lane = tid & 63;
  const int wid = tid >> 6;
  const int lo = lane & 31;
  const int hi = lane >> 5;
  const int hp = blockIdx.x & 1;
  const int n = (blockIdx.x >> 1) & 255;
  const int b = blockIdx.x >> 9;
  const long base = (long)b * 4194304 + n * 64 + hp * 32;

  // ---- staged projections (q -> registers; k,v -> LDS) ----
  stage_lin(xq + base, lds, LINQ, tid);
  __syncthreads();                                   // 1
  lin_to_xs(lds, LINQ, tid);
  __syncthreads();                                   // 2
  s8v qf[2];
  stage_lin(xk + base, lds, LINKV, tid);             // overlaps proj_Q
  proj_Q(lds, wb + 0, bq, qf, wid, lo, hi);
  __syncthreads();                                   // 3
  lin_to_xs(lds, LINKV, tid);
  __syncthreads();                                   // 4
  stage_lin(xv + base, lds, LINKV, tid);             // overlaps proj_K
  proj_K(lds, wb + 65536, bk, wid, lo, hi);
  __syncthreads();                                   // 5
  lin_to_xs(lds, LINKV, tid);
  __syncthreads();                                   // 6
  proj_V(lds, wb + 131072, bv, wid, lo, hi);
  __syncthreads();                                   // 7

  // ---- attention: online softmax over e-tiles, heads sequential ----
  f16v z16;
#pragma unroll
  for (int i = 0; i < 16; ++i) z16[i] = 0.f;
  const int l15 = lane & 15;

#pragma unroll
  for (int h = 0; h < 2; ++h) {
    float m = 0.f, sm = 0.f;
    f16v ot;
#pragma unroll
    for (int i = 0; i < 16; ++i) ot[i] = 0.f;

#pragma unroll
    for (int et = 0; et < 8; ++et) {
      const s8v kf = *reinterpret_cast<const s8v*>(
          &lds[KT + (2 * h + hi) * 2048 + (et * 32 + lo) * 8]);
      f16v st = __builtin_amdgcn_mfma_f32_32x32x16_bf16(kf, qf[h], z16, 0, 0, 0);

      // depth-4 tree max over 16, then cross-half combine
      float t[8];
#pragma unroll
      for (int i = 0; i < 8; ++i) t[i] = fmaxf(st[i], st[i + 8]);
#pragma unroll
      for (int i = 0; i < 4; ++i) t[i] = fmaxf(t[i], t[i + 4]);
      const float tm = xh_max(fmaxf(fmaxf(t[0], t[1]), fmaxf(t[2], t[3])));

      if (et == 0) {
        m = tm;                          // peel: no rescale on first tile
      } else {
        const float mn = fmaxf(m, tm);
        const float f = __builtin_amdgcn_exp2f(m - mn);
        m = mn;
        sm *= f;
#pragma unroll
        for (int i = 0; i < 16; ++i) ot[i] *= f;
      }
      // p = exp2(st - m) in place (q pre-scaled by 0.25*log2e)
#pragma unroll
      for (int i = 0; i < 16; ++i) st[i] = __builtin_amdgcn_exp2f(st[i] - m);
      float s[8];
#pragma unroll
      for (int i = 0; i < 8; ++i) s[i] = st[i] + st[i + 8];
#pragma unroll
      for (int i = 0; i < 4; ++i) s[i] = s[i] + s[i + 4];
      sm += (s[0] + s[1]) + (s[2] + s[3]);

      // PV accumulate: 2 k-steps of 16, shfl-halved P exchange
#pragma unroll
      for (int s2 = 0; s2 < 2; ++s2) {
        const int ks = 2 * et + s2;
        const s8v vf = *reinterpret_cast<const s8v*>(
            &lds[VT + (2 * ks + hi) * 256 + (h * 16 + l15) * 8]);
        const int q = s2 * 8;
        const u32 x0 = pk2(st[q + 0], st[q + 1]);
        const u32 x1 = pk2(st[q + 2], st[q + 3]);
        const u32 y0 = pk2(st[q + 4], st[q + 5]);
        const u32 y1 = pk2(st[q + 6], st[q + 7]);
        // hi=0 needs partner's x0,x1 ; hi=1 needs partner's y0,y1
        const u32 z0 = hi ? x0 : y0;
        const u32 z1 = hi ? x1 : y1;
        const u32 s0 = (u32)__shfl_xor((int)z0, 32);
        const u32 s1 = (u32)__shfl_xor((int)z1, 32);
        union { u32 u[4]; s8v v; } bu;
        bu.u[0] = hi ? s0 : x0;
        bu.u[1] = hi ? s1 : x1;
        bu.u[2] = hi ? y0 : s0;
        bu.u[3] = hi ? y1 : s1;
        ot = __builtin_amdgcn_mfma_f32_32x32x16_bf16(vf, bu.v, ot, 0, 0, 0);
      }
    }
    // finalize + store O^T into ATT (@XS): [dblk][l][j]
    const float rinv = 1.0f / xh_sum(sm);
    const int d = wid * 32 + lo;
#pragma unroll
    for (int r = 0; r < 8; ++r) {
      const int lh = (r & 3) + 8 * (r >> 2) + 4 * hi;   // 0..15
      const int l = h * 16 + lh;
      lds[XS + (d >> 3) * 256 + l * 8 + (d & 7)] = f2bf(ot[r] * rinv);
    }
  }
  __syncthreads();                                   // 8

  proj_O(lds, wb + 196608, bo, out, base, wid, lo, hi);
}

extern "C" void kernel_launch(void* const* d_in, const int* in_sizes, int n_in,
                              void* d_out, int out_size, void* d_ws, size_t ws_size,
                              hipStream_t stream) {
  const float* xq = (const float*)d_in[0];
  const float* xk = (const float*)d_in[1];
  const float* xv = (const float*)d_in[2];
  const float* wq = (const float*)d_in[3];
  const float* bq = (const float*)d_in[4];
  const float* wk = (const float*)d_in[5];
  const float* bk = (const float*)d_in[6];
  const float* wv = (const float*)d_in[7];
  const float* bv = (const float*)d_in[8];
  const float* wo = (const float*)d_in[9];
  const float* bo = (const float*)d_in[10];
  u16* wsb = (u16*)d_ws;  // 4 * 65536 bf16 = 512 KB
  float* out = (float*)d_out;

  cvt_weights<<<dim3(256), dim3(256), 0, stream>>>(wq, wk, wv, wo, wsb);
  mha_kernel<<<dim3(2048), dim3(512), 0, stream>>>(xq, xk, xv, wsb, bq, bk, bv, bo, out);
}

// Round 8
// 243.752 us; speedup vs baseline: 1.6031x; 1.6031x over previous
//
#include <hip/hip_runtime.h>

// B=4, DIN=DM=256, N=256, L=64, H=4, LH=16.
// Block = (b, n, head-pair): grid = 2048, 512 threads (8 waves).
// Round-8: r7 compute path (passing) with (a) plain __launch_bounds__(512) -- the
// (512,6) min-clause forced VGPR=40 + ~1.2GB/dispatch scratch spills in r7;
// (b) direct-to-blocked staging (global->reg->pk2->ds_write_b128), XS double-buffered:
// barriers 8->5, no linear staging region, LDS 64KB -> 2 blocks/CU.
// Inline-asm cvt_pk and launch-bounds min-clause are BANNED (r3/r4/r7 evidence).

typedef unsigned int u32;
typedef unsigned short u16;
typedef __attribute__((ext_vector_type(8))) short s8v;    // 8 x bf16
typedef __attribute__((ext_vector_type(16))) float f16v;  // 16 x f32 acc

// LDS regions (u16 indices):
//   XS0/XS1: X^T blocked [cblk 0..31][l 0..31][j 0..7] (8192 each); XS1 holds ATT later
//   KT: k^T blocked [lblk 0..3][o 0..255][j 0..7] (8192)
//   VT: v blocked   [eblk 0..31][l 0..31][j 0..7] (8192)
#define XS0 0
#define XS1 8192
#define KT 16384
#define VT 24576
#define LDS_TOT 32768   // 64 KB -> 2 blocks/CU

#define QSCALE 0.360673760222f   // 0.25 * log2(e)

__device__ __forceinline__ u16 f2bf(float x) {          // RNE bit-twiddle (verified)
  union { float f; u32 u; } c; c.f = x;
  return (u16)((c.u + 0x7FFFu + ((c.u >> 16) & 1u)) >> 16);
}
__device__ __forceinline__ u32 pk2(float a, float b) {  // lo=a, hi=b (verified)
  return (u32)f2bf(a) | ((u32)f2bf(b) << 16);
}
__device__ __forceinline__ float xh_max(float v) { return fmaxf(v, __shfl_xor(v, 32)); }
__device__ __forceinline__ float xh_sum(float v) { return v + __shfl_xor(v, 32); }

__global__ void cvt_weights(const float* __restrict__ wq, const float* __restrict__ wk,
                            const float* __restrict__ wv, const float* __restrict__ wo,
                            u16* __restrict__ out) {
  int i = blockIdx.x * 256 + threadIdx.x;  // 0..65535
  out[i]          = f2bf(wq[i]);
  out[i + 65536]  = f2bf(wk[i]);
  out[i + 131072] = f2bf(wv[i]);
  out[i + 196608] = f2bf(wo[i]);
}

// global fp32 X[c][l-window 32] -> blocked bf16 XS[cblk][l][j] directly.
// item (cb,l): 8 scalar loads (wave: 2 rows x 128B, fully coalesced) -> 4 pk2 -> b128.
__device__ __forceinline__ void stage_blk(const float* __restrict__ src, u16* lds,
                                          int dstoff, int tid) {
#pragma unroll
  for (int it = 0; it < 2; ++it) {
    const int idx = it * 512 + tid;       // (cb, l)
    const int l = idx & 31, cb = idx >> 5;
    const float* p = src + (cb * 8) * 16384 + l;
    float x[8];
#pragma unroll
    for (int j = 0; j < 8; ++j) x[j] = p[j * 16384];
    union { u32 u[4]; s8v v; } pw;
    pw.u[0] = pk2(x[0], x[1]);
    pw.u[1] = pk2(x[2], x[3]);
    pw.u[2] = pk2(x[4], x[5]);
    pw.u[3] = pk2(x[6], x[7]);
    *reinterpret_cast<s8v*>(&lds[dstoff + cb * 256 + l * 8]) = pw.v;
  }
}

// q projection -> B-frags in registers (r7-verified).
__device__ __forceinline__ void proj_Q(u16* lds, int xs, const u16* __restrict__ w,
                                       const float* __restrict__ bias,
                                       s8v qf[2], int wid, int lo, int hi) {
  const int o = wid * 32 + lo;
  f16v a;
#pragma unroll
  for (int i = 0; i < 16; ++i) a[i] = 0.f;
#pragma unroll
  for (int s = 0; s < 16; ++s) {
    const s8v bw = *reinterpret_cast<const s8v*>(w + o * 256 + s * 16 + hi * 8);
    const s8v xf = *reinterpret_cast<const s8v*>(&lds[xs + (2 * s + hi) * 256 + lo * 8]);
    a = __builtin_amdgcn_mfma_f32_32x32x16_bf16(xf, bw, a, 0, 0, 0);
  }
  const float bb = bias[o];
  u32 W[8];
#pragma unroll
  for (int g = 0; g < 4; ++g) {
    W[2 * g]     = pk2((a[4 * g + 0] + bb) * QSCALE, (a[4 * g + 1] + bb) * QSCALE);
    W[2 * g + 1] = pk2((a[4 * g + 2] + bb) * QSCALE, (a[4 * g + 3] + bb) * QSCALE);
  }
#pragma unroll
  for (int h = 0; h < 2; ++h) {
    const int bse = 4 * h;
    const u32 z0 = hi ? W[bse + 0] : W[bse + 2];
    const u32 z1 = hi ? W[bse + 1] : W[bse + 3];
    const u32 s0 = (u32)__shfl_xor((int)z0, 32);
    const u32 s1 = (u32)__shfl_xor((int)z1, 32);
    union { u32 u[4]; s8v v; } fu;
    fu.u[0] = hi ? s0 : W[bse + 0];
    fu.u[1] = hi ? s1 : W[bse + 1];
    fu.u[2] = hi ? W[bse + 2] : s0;
    fu.u[3] = hi ? W[bse + 3] : s1;
    qf[h] = fu.v;
  }
}

// k^T: D[l][o] -> KT [lblk][o][j]  (r7-verified)
__device__ __forceinline__ void proj_K(u16* lds, int xs, const u16* __restrict__ w,
                                       const float* __restrict__ bias,
                                       int wid, int lo, int hi) {
  const int o = wid * 32 + lo;
  f16v a;
#pragma unroll
  for (int i = 0; i < 16; ++i) a[i] = 0.f;
#pragma unroll
  for (int s = 0; s < 16; ++s) {
    const s8v bw = *reinterpret_cast<const s8v*>(w + o * 256 + s * 16 + hi * 8);
    const s8v xf = *reinterpret_cast<const s8v*>(&lds[xs + (2 * s + hi) * 256 + lo * 8]);
    a = __builtin_amdgcn_mfma_f32_32x32x16_bf16(xf, bw, a, 0, 0, 0);
  }
  const float bb = bias[o];
#pragma unroll
  for (int g = 0; g < 4; ++g) {
    uint2 wv2;
    wv2.x = pk2(a[4 * g + 0] + bb, a[4 * g + 1] + bb);
    wv2.y = pk2(a[4 * g + 2] + bb, a[4 * g + 3] + bb);
    *reinterpret_cast<uint2*>(&lds[KT + g * 2048 + o * 8 + hi * 4]) = wv2;
  }
}

// v: D[e][l] -> VT [eblk][l][j]  (r7-verified)
__device__ __forceinline__ void proj_V(u16* lds, int xs, const u16* __restrict__ w,
                                       const float* __restrict__ bias,
                                       int wid, int lo, int hi) {
  const int e0 = wid * 32;
  const int e = e0 + lo;
  f16v a;
#pragma unroll
  for (int i = 0; i < 16; ++i) a[i] = 0.f;
#pragma unroll
  for (int s = 0; s < 16; ++s) {
    const s8v aw = *reinterpret_cast<const s8v*>(w + e * 256 + s * 16 + hi * 8);
    const s8v xf = *reinterpret_cast<const s8v*>(&lds[xs + (2 * s + hi) * 256 + lo * 8]);
    a = __builtin_amdgcn_mfma_f32_32x32x16_bf16(aw, xf, a, 0, 0, 0);
  }
#pragma unroll
  for (int g = 0; g < 4; ++g) {
    const int eb = e0 + 8 * g + 4 * hi;
    uint2 wv2;
    wv2.x = pk2(a[4 * g + 0] + bias[eb + 0], a[4 * g + 1] + bias[eb + 1]);
    wv2.y = pk2(a[4 * g + 2] + bias[eb + 2], a[4 * g + 3] + bias[eb + 3]);
    *reinterpret_cast<uint2*>(&lds[VT + (4 * wid + g) * 256 + lo * 8 + hi * 4]) = wv2;
  }
}

// out[o][l] = sum_d Wo[o][d] att[d][l] + bo[o]  (att in XS1)
__device__ __forceinline__ void proj_O(u16* lds, int xs, const u16* __restrict__ w,
                                       const float* __restrict__ bias,
                                       float* __restrict__ out, long obase,
                                       int wid, int lo, int hi) {
  const int o0 = wid * 32;
  const int o = o0 + lo;
  f16v a;
#pragma unroll
  for (int i = 0; i < 16; ++i) a[i] = 0.f;
#pragma unroll
  for (int s = 0; s < 16; ++s) {
    const s8v aw = *reinterpret_cast<const s8v*>(w + o * 256 + s * 16 + hi * 8);
    const s8v bf = *reinterpret_cast<const s8v*>(&lds[xs + (2 * s + hi) * 256 + lo * 8]);
    a = __builtin_amdgcn_mfma_f32_32x32x16_bf16(aw, bf, a, 0, 0, 0);
  }
#pragma unroll
  for (int r = 0; r < 16; ++r) {
    const int orow = o0 + (r & 3) + 8 * (r >> 2) + 4 * hi;
    out[obase + orow * 16384 + lo] = a[r] + bias[orow];
  }
}

__global__ __launch_bounds__(512)
void mha_kernel(const float* __restrict__ xq, const float* __restrict__ xk,
                const float* __restrict__ xv, const u16* __restrict__ wb,
                const float* __restrict__ bq, const float* __restrict__ bk,
                const float* __restrict__ bv, const float* __restrict__ bo,
                float* __restrict__ out) {
  __shared__ __align__(16) u16 lds[LDS_TOT];
  const int tid = threadIdx.x;
  const int lane = tid & 63;
  const int wid = tid >> 6;
  const int lo = lane & 31;
  const int hi = lane >> 5;
  const int hp = blockIdx.x & 1;
  const int n = (blockIdx.x >> 1) & 255;
  const int b = blockIdx.x >> 9;
  const long base = (long)b * 4194304 + n * 64 + hp * 32;

  // ---- staged projections: 5 barriers total ----
  stage_blk(xq + base, lds, XS0, tid);
  __syncthreads();                                   // 1: XS0(q) ready
  s8v qf[2];
  stage_blk(xk + base, lds, XS1, tid);               // overlaps proj_Q
  proj_Q(lds, XS0, wb + 0, bq, qf, wid, lo, hi);
  __syncthreads();                                   // 2: XS1(k) ready, XS0 free
  stage_blk(xv + base, lds, XS0, tid);               // overlaps proj_K
  proj_K(lds, XS1, wb + 65536, bk, wid, lo, hi);
  __syncthreads();                                   // 3: XS0(v) ready
  proj_V(lds, XS0, wb + 131072, bv, wid, lo, hi);
  __syncthreads();                                   // 4: KT, VT ready

  // ---- attention: online softmax over e-tiles, heads sequential (r7-verified) ----
  f16v z16;
#pragma unroll
  for (int i = 0; i < 16; ++i) z16[i] = 0.f;
  const int l15 = lane & 15;

#pragma unroll
  for (int h = 0; h < 2; ++h) {
    float m = 0.f, sm = 0.f;
    f16v ot;
#pragma unroll
    for (int i = 0; i < 16; ++i) ot[i] = 0.f;

#pragma unroll
    for (int et = 0; et < 8; ++et) {
      const s8v kf = *reinterpret_cast<const s8v*>(
          &lds[KT + (2 * h + hi) * 2048 + (et * 32 + lo) * 8]);
      f16v st = __builtin_amdgcn_mfma_f32_32x32x16_bf16(kf, qf[h], z16, 0, 0, 0);

      float t[8];
#pragma unroll
      for (int i = 0; i < 8; ++i) t[i] = fmaxf(st[i], st[i + 8]);
#pragma unroll
      for (int i = 0; i < 4; ++i) t[i] = fmaxf(t[i], t[i + 4]);
      const float tm = xh_max(fmaxf(fmaxf(t[0], t[1]), fmaxf(t[2], t[3])));

      if (et == 0) {
        m = tm;                          // peel
      } else {
        const float mn = fmaxf(m, tm);
        const float f = __builtin_amdgcn_exp2f(m - mn);
        m = mn;
        sm *= f;
#pragma unroll
        for (int i = 0; i < 16; ++i) ot[i] *= f;
      }
#pragma unroll
      for (int i = 0; i < 16; ++i) st[i] = __builtin_amdgcn_exp2f(st[i] - m);
      float s[8];
#pragma unroll
      for (int i = 0; i < 8; ++i) s[i] = st[i] + st[i + 8];
#pragma unroll
      for (int i = 0; i < 4; ++i) s[i] = s[i] + s[i + 4];
      sm += (s[0] + s[1]) + (s[2] + s[3]);

#pragma unroll
      for (int s2 = 0; s2 < 2; ++s2) {
        const int ks = 2 * et + s2;
        const s8v vf = *reinterpret_cast<const s8v*>(
            &lds[VT + (2 * ks + hi) * 256 + (h * 16 + l15) * 8]);
        const int q = s2 * 8;
        const u32 x0 = pk2(st[q + 0], st[q + 1]);
        const u32 x1 = pk2(st[q + 2], st[q + 3]);
        const u32 y0 = pk2(st[q + 4], st[q + 5]);
        const u32 y1 = pk2(st[q + 6], st[q + 7]);
        const u32 z0 = hi ? x0 : y0;
        const u32 z1 = hi ? x1 : y1;
        const u32 s0 = (u32)__shfl_xor((int)z0, 32);
        const u32 s1 = (u32)__shfl_xor((int)z1, 32);
        union { u32 u[4]; s8v v; } bu;
        bu.u[0] = hi ? s0 : x0;
        bu.u[1] = hi ? s1 : x1;
        bu.u[2] = hi ? y0 : s0;
        bu.u[3] = hi ? y1 : s1;
        ot = __builtin_amdgcn_mfma_f32_32x32x16_bf16(vf, bu.v, ot, 0, 0, 0);
      }
    }
    // finalize + store O^T into ATT (@XS1): [dblk][l][j]
    const float rinv = 1.0f / xh_sum(sm);
    const int d = wid * 32 + lo;
#pragma unroll
    for (int r = 0; r < 8; ++r) {
      const int lh = (r & 3) + 8 * (r >> 2) + 4 * hi;   // 0..15
      const int l = h * 16 + lh;
      lds[XS1 + (d >> 3) * 256 + l * 8 + (d & 7)] = f2bf(ot[r] * rinv);
    }
  }
  __syncthreads();                                   // 5: ATT ready

  proj_O(lds, XS1, wb + 196608, bo, out, base, wid, lo, hi);
}

extern "C" void kernel_launch(void* const* d_in, const int* in_sizes, int n_in,
                              void* d_out, int out_size, void* d_ws, size_t ws_size,
                              hipStream_t stream) {
  const float* xq = (const float*)d_in[0];
  const float* xk = (const float*)d_in[1];
  const float* xv = (const float*)d_in[2];
  const float* wq = (const float*)d_in[3];
  const float* bq = (const float*)d_in[4];
  const float* wk = (const float*)d_in[5];
  const float* bk = (const float*)d_in[6];
  const float* wv = (const float*)d_in[7];
  const float* bv = (const float*)d_in[8];
  const float* wo = (const float*)d_in[9];
  const float* bo = (const float*)d_in[10];
  u16* wsb = (u16*)d_ws;  // 4 * 65536 bf16 = 512 KB
  float* out = (float*)d_out;

  cvt_weights<<<dim3(256), dim3(256), 0, stream>>>(wq, wk, wv, wo, wsb);
  mha_kernel<<<dim3(2048), dim3(512), 0, stream>>>(xq, xk, xv, wsb, bq, bk, bv, bo, out);
}